// Round 19
// baseline (162.659 us; speedup 1.0000x reference)
//
#include <hip/hip_runtime.h>

#define TT   110          // max_seq_len
#define BBD  256          // num dialogues
#define NND  28160        // TT*BBD
#define WIN  10

typedef __bf16 bf16x8 __attribute__((ext_vector_type(8)));
typedef __bf16 bf16x4 __attribute__((ext_vector_type(4)));
typedef float  f32x4  __attribute__((ext_vector_type(4)));

__device__ __forceinline__ int imax(int a, int b){ return a > b ? a : b; }
__device__ __forceinline__ int imin(int a, int b){ return a < b ? a : b; }

// All per-node matrices are SOURCE-MAJOR: row m = t*256 + b  (node n = b*110+t).
// Weight images (bf16, pre-swizzled per 64-col tile, row=col, KSP elems):
//   Wfimg [4][64][320] @ img+0
//   wrimg [9][64][256] @ img+81920
//   Wmaimg[5][64][320] @ img+229376
//   Wlimg [1][64][320] @ img+331776
//   Wgcimg[1][64][128] @ img+352256
// Image storage: source k-chunk c (8 bf16) stored at chunk position c^(col&7).

// ---------------------------------------------------------------------------
// K0: Wrels[r][f][h] = sum_nb comp[r][nb]*basis[nb][f][h]  (r<8); Wrels[8]=root
// ---------------------------------------------------------------------------
__global__ __launch_bounds__(256) void wrels_k(
    const float* __restrict__ basis, const float* __restrict__ comp,
    const float* __restrict__ root, float* __restrict__ wrels)
{
  int idx = blockIdx.x * 256 + threadIdx.x;        // 9*12800 = 115200
  if (idx >= 115200) return;
  int r = idx / 12800, fh = idx % 12800;
  float v;
  if (r < 8) {
    v = 0.f;
    #pragma unroll
    for (int nb = 0; nb < 30; ++nb) v += comp[r*30 + nb] * basis[nb*12800 + fh];
  } else {
    v = root[fh];
  }
  wrels[idx] = v;
}

// ---------------------------------------------------------------------------
// prep_k: build all bf16 pre-swizzled weight tile images (wrels precomputed).
// ---------------------------------------------------------------------------
__global__ __launch_bounds__(256) void prep_k(
    const float* __restrict__ wrels, const float* __restrict__ Wf,
    const float* __restrict__ Wma, const float* __restrict__ Wl,
    const float* __restrict__ Wrel, const float* __restrict__ Wroot2,
    __bf16* __restrict__ img)
{
  constexpr int T1 = 10240;              // Wf   4*64*40
  constexpr int T2 = T1 + 18432;         // wrels 9*64*32
  constexpr int T3 = T2 + 12800;         // Wma  5*64*40
  constexpr int T4 = T3 + 2560;          // Wl   64*40
  constexpr int T5 = T4 + 1024;          // Wgc  64*16
  for (int c = blockIdx.x * 256 + threadIdx.x; c < T5; c += gridDim.x * 256) {
    bf16x8 v;
    __bf16* dst;
    if (c < T1) {
      const int r = c;
      const int cb = r / 2560, r2 = r - cb * 2560;
      const int col = r2 / 40, ch = r2 - col * 40;
      const int cs = (ch & ~7) | ((ch ^ col) & 7);
      const int gc = (cb << 6) + col;
      #pragma unroll
      for (int e = 0; e < 8; ++e) {
        const int k = (cs << 3) + e;
        v[e] = (__bf16)((k < 300 && gc < 200) ? Wf[k*200 + gc] : 0.f);
      }
      dst = img + cb * 20480 + col * 320 + (ch << 3);
    } else if (c < T2) {
      const int r = c - T1;
      const int cb = r >> 11, r2 = r & 2047;
      const int col = r2 >> 5, ch = r2 & 31;
      const int cs = (ch & ~7) | ((ch ^ col) & 7);
      #pragma unroll
      for (int e = 0; e < 8; ++e) {
        const int k = (cs << 3) + e;
        v[e] = (__bf16)((k < 200) ? wrels[cb*12800 + k*64 + col] : 0.f);
      }
      dst = img + 81920 + cb * 16384 + col * 256 + (ch << 3);
    } else if (c < T3) {
      const int r = c - T2;
      const int cb = r / 2560, r2 = r - cb * 2560;
      const int col = r2 / 40, ch = r2 - col * 40;
      const int cs = (ch & ~7) | ((ch ^ col) & 7);
      const int gc = (cb << 6) + col;
      #pragma unroll
      for (int e = 0; e < 8; ++e) {
        const int k = (cs << 3) + e;
        v[e] = (__bf16)((k < 264 && gc < 264) ? Wma[k*264 + gc] : 0.f);
      }
      dst = img + 229376 + cb * 20480 + col * 320 + (ch << 3);
    } else if (c < T4) {
      const int r = c - T3;
      const int col = r / 40, ch = r - col * 40;
      const int cs = (ch & ~7) | ((ch ^ col) & 7);
      #pragma unroll
      for (int e = 0; e < 8; ++e) {
        const int k = (cs << 3) + e;
        v[e] = (__bf16)((k < 264) ? Wl[k*64 + col] : 0.f);
      }
      dst = img + 331776 + col * 320 + (ch << 3);
    } else {
      const int r = c - T4;
      const int col = r / 16, ch = r - col * 16;
      const int cs = (ch & ~7) | ((ch ^ col) & 7);
      #pragma unroll
      for (int e = 0; e < 8; ++e) {
        const int k = (cs << 3) + e;
        v[e] = (__bf16)((k < 64) ? Wrel[k*64 + col] : Wroot2[(k-64)*64 + col]);
      }
      dst = img + 352256 + col * 128 + (ch << 3);
    }
    *(bf16x8*)dst = v;
  }
}

// ---------------------------------------------------------------------------
// bgemm0_k: fusion GEMM with A staged through LDS (round 19).
// A rows (64 x 300 f32) read ROW-CONTIGUOUS coalesced, converted bf16,
// written swizzled to Ash; B image copied to Bsh. 80 KB LDS, 2 blocks/CU.
// ---------------------------------------------------------------------------
__global__ __launch_bounds__(256) void bgemm0_k(
    const float* __restrict__ a0, const float* __restrict__ a1,
    const float* __restrict__ a2, const __bf16* __restrict__ Bimg,
    const float* __restrict__ bias, __bf16* __restrict__ Cv)
{
  __shared__ __align__(16) __bf16 Ash[64][320];
  __shared__ __align__(16) __bf16 Bsh[64][320];
  const int tid = threadIdx.x;
  constexpr int NWT = 1760, q = NWT >> 3;
  const int bid = blockIdx.x;
  const int w = (bid & 7) * q + (bid >> 3);
  const int m0 = (w >> 2) << 6;
  const int cb = w & 3;
  const int n0 = cb << 6;

  { // ---- stage B (image copy) + A (coalesced f32 -> bf16, swizzled) ----
    const bf16x8* srcB = (const bf16x8*)(Bimg + (size_t)cb * (64 * 320));
    bf16x8* dstB = (bf16x8*)&Bsh[0][0];
    #pragma unroll
    for (int c = 0; c < 10; ++c) dstB[c * 256 + tid] = srcB[c * 256 + tid];
    // A: 2560 chunks (row, ch), 10 iters; chunk data from source chunk cs
    #pragma unroll
    for (int it = 0; it < 10; ++it) {
      const int i = it * 256 + tid;
      const int row = i / 40, ch = i - row * 40;
      const int cs = (ch & ~7) | ((ch ^ row) & 7);
      const size_t ab = (size_t)(m0 + row) * 100;
      float4 u[2];
      #pragma unroll
      for (int h = 0; h < 2; ++h) {
        const int g4 = (cs << 3) + (h << 2);
        if (g4 < 100)      u[h] = *(const float4*)(a0 + ab + g4);
        else if (g4 < 200) u[h] = *(const float4*)(a1 + ab + g4 - 100);
        else if (g4 < 300) u[h] = *(const float4*)(a2 + ab + g4 - 200);
        else               u[h] = make_float4(0.f,0.f,0.f,0.f);
      }
      *(bf16x8*)&Ash[row][ch << 3] =
        (bf16x8){(__bf16)u[0].x,(__bf16)u[0].y,(__bf16)u[0].z,(__bf16)u[0].w,
                 (__bf16)u[1].x,(__bf16)u[1].y,(__bf16)u[1].z,(__bf16)u[1].w};
    }
  }
  __syncthreads();

  const int wid = tid >> 6, lane = tid & 63;
  const int wm = wid >> 1, wn = wid & 1;
  const int fr = lane & 15;
  const int fk = (lane >> 4) << 3;
  const int row0 = (lane >> 4) << 2;

  f32x4 acc[2][2];
  #pragma unroll
  for (int f = 0; f < 2; ++f)
    #pragma unroll
    for (int g = 0; g < 2; ++g) acc[f][g] = (f32x4){0.f,0.f,0.f,0.f};

  #pragma unroll
  for (int kt = 0; kt < 10; ++kt) {
    const int ko = (kt << 5) + fk;
    bf16x8 af[2], bfv[2];
    #pragma unroll
    for (int f = 0; f < 2; ++f) {
      const int ra = wm*32 + f*16 + fr;
      af[f] = *(const bf16x8*)&Ash[ra][(((ko >> 3) ^ (ra & 7)) << 3)];
    }
    #pragma unroll
    for (int g = 0; g < 2; ++g) {
      const int rb_ = wn*32 + g*16 + fr;
      bfv[g] = *(const bf16x8*)&Bsh[rb_][(((ko >> 3) ^ (rb_ & 7)) << 3)];
    }
    #pragma unroll
    for (int f = 0; f < 2; ++f)
      #pragma unroll
      for (int g = 0; g < 2; ++g)
        acc[f][g] = __builtin_amdgcn_mfma_f32_16x16x32_bf16(af[f], bfv[g], acc[f][g], 0, 0, 0);
  }

  #pragma unroll
  for (int f = 0; f < 2; ++f) {
    const int gm0 = m0 + wm*32 + f*16 + row0;
    #pragma unroll
    for (int g = 0; g < 2; ++g) {
      const int col = n0 + wn*32 + g*16 + fr;
      if (col < 200) {
        const float bv = bias[col];
        #pragma unroll
        for (int r2 = 0; r2 < 4; ++r2)
          Cv[(size_t)(gm0 + r2) * 200 + col] = (__bf16)(acc[f][g][r2] + bv);
      }
    }
  }
}

// ---------------------------------------------------------------------------
// bgemm: B-resident MFMA GEMM, pre-swizzled B image (modes 1, 2).
// ---------------------------------------------------------------------------
template<int MODE, int NK, int KSP, int NCB>
__global__ __launch_bounds__(256) void bgemm_k(
    const void* __restrict__ a0, const void* __restrict__ a1,
    const __bf16* __restrict__ Bimg, const float* __restrict__ bias,
    __bf16* __restrict__ Cv, int Ncols, const int* __restrict__ spkm)
{
  __shared__ __align__(16) __bf16 Bsh[64][KSP];
  const int tid = threadIdx.x;
  constexpr int NWT = 440 * NCB;
  constexpr int q = NWT >> 3;
  const int bid = blockIdx.x;
  const int w = (bid & 7) * q + (bid >> 3);
  const int m0 = (w / NCB) << 6;
  const int cb = w % NCB;
  const int n0 = cb << 6;

  {
    const bf16x8* src = (const bf16x8*)(Bimg + (size_t)cb * (64 * KSP));
    bf16x8* dst = (bf16x8*)&Bsh[0][0];
    constexpr int NIT = (64 * KSP / 8) / 256;
    #pragma unroll
    for (int c = 0; c < NIT; ++c) dst[c * 256 + tid] = src[c * 256 + tid];
  }
  __syncthreads();

  const int wid = tid >> 6, lane = tid & 63;
  const int wm = wid >> 1, wn = wid & 1;
  const int fr = lane & 15;
  const int fk = (lane >> 4) << 3;
  const int row0 = (lane >> 4) << 2;

  f32x4 acc[2][2];
  #pragma unroll
  for (int f = 0; f < 2; ++f)
    #pragma unroll
    for (int g = 0; g < 2; ++g) acc[f][g] = (f32x4){0.f,0.f,0.f,0.f};

  #pragma unroll
  for (int kt = 0; kt < NK; ++kt) {
    const int ko = (kt << 5) + fk;
    bf16x8 af[2];
    #pragma unroll
    for (int f = 0; f < 2; ++f) {
      const int ra = m0 + wm*32 + f*16 + fr;
      if constexpr (MODE == 2) {
        af[f] = (ko < 200)
              ? *(const bf16x8*)((const __bf16*)a0 + (size_t)ra*200 + ko)
              : *(const bf16x8*)((const __bf16*)a1 + (size_t)ra*64 + (ko - 200));
      } else {
        af[f] = *(const bf16x8*)((const __bf16*)a0 + (size_t)ra*200 + ko);
      }
    }
    bf16x8 bfv[2];
    #pragma unroll
    for (int g = 0; g < 2; ++g) {
      const int rb_ = wn*32 + g*16 + fr;
      bfv[g] = *(const bf16x8*)&Bsh[rb_][(((ko >> 3) ^ (rb_ & 7)) << 3)];
    }
    #pragma unroll
    for (int f = 0; f < 2; ++f)
      #pragma unroll
      for (int g = 0; g < 2; ++g)
        acc[f][g] = __builtin_amdgcn_mfma_f32_16x16x32_bf16(af[f], bfv[g], acc[f][g], 0, 0, 0);
  }

  #pragma unroll
  for (int f = 0; f < 2; ++f) {
    const int gm0 = m0 + wm*32 + f*16 + row0;
    int sp[4];
    if constexpr (MODE == 1) {
      #pragma unroll
      for (int r2 = 0; r2 < 4; ++r2) sp[r2] = spkm[gm0 + r2];
    }
    #pragma unroll
    for (int g = 0; g < 2; ++g) {
      const int col = n0 + wn*32 + g*16 + fr;
      if (col < Ncols) {
        const float bv = bias ? bias[col] : 0.f;
        #pragma unroll
        for (int r2 = 0; r2 < 4; ++r2) {
          const float v = acc[f][g][r2] + bv;
          const int gm = gm0 + r2;
          bool dow = true;
          if constexpr (MODE == 1) dow = (cb == 8) || ((cb >> 2) == sp[r2]);
          if (dow) Cv[(size_t)gm * Ncols + col] = (__bf16)v;
        }
      }
    }
  }
}

// ---------------------------------------------------------------------------
// dialog_k: fused RGCN mean-agg + window-sum + GraphConv GEMM (round-14 cfg).
// ---------------------------------------------------------------------------
__global__ __launch_bounds__(512) void dialog_k(
    const __bf16* __restrict__ xr, const int* __restrict__ spk,
    const float* __restrict__ brg, const __bf16* __restrict__ Wgcimg,
    const float* __restrict__ brel, __bf16* __restrict__ h2)
{
  __shared__ __align__(16) __bf16 Xsh[75][320];
  __shared__ float  h1f[65][68];
  __shared__ __align__(16) __bf16 aggbf[56][72];
  __shared__ int ssp[TT];
  __shared__ int pc[TT + 1];
  const int bid = blockIdx.x;
  const int b = bid >> 1, half = bid & 1;
  const int t0   = half ? 55 : 0;
  const int H1LO = half ? 45 : 0;
  const int XLO  = half ? 35 : 0;
  const int tid = threadIdx.x;
  if (tid < TT) ssp[tid] = spk[tid * BBD + b];
  __syncthreads();
  if (tid < 64) {
    int v = (tid < TT) ? ssp[tid] : 0;
    #pragma unroll
    for (int o = 1; o < 64; o <<= 1) { const int u = __shfl_up(v, o); if (tid >= o) v += u; }
    pc[tid + 1] = v;
    const int tot = __shfl(v, 63);
    int v2 = (tid + 64 < TT) ? ssp[tid + 64] : 0;
    #pragma unroll
    for (int o = 1; o < 64; o <<= 1) { const int u = __shfl_up(v2, o); if (tid >= o) v2 += u; }
    if (tid + 64 < TT) pc[tid + 65] = tot + v2;
    if (tid == 0) pc[0] = 0;
  }
  for (int i = tid << 3; i < 75 * 320; i += 512 << 3) {
    const int xl = i / 320, off = i - xl * 320;
    const int j = XLO + xl;
    const size_t base = ((size_t)j * BBD + b) * 576;
    const int col = (off < 256) ? ((ssp[j] << 8) + off) : (256 + off);
    *(bf16x8*)&Xsh[xl][off] = *(const bf16x8*)&xr[base + col];
  }
  __syncthreads();
  const int w8 = tid >> 6, lane = tid & 63;
  const float bias = brg[lane];
  for (int lh = w8; lh < 65; lh += 8) {
    const int t = H1LO + lh;
    const int si2 = ssp[t] << 1;
    const int jlo = imax(t - WIN, 0), jhi = imin(t + WIN, TT - 1);
    const int n1d0 = pc[t] - pc[jlo];
    const int n0d0 = (t - jlo) - n1d0;
    const int n1d1 = pc[jhi + 1] - pc[t];
    const int n0d1 = (jhi - t + 1) - n1d1;
    const float r00 = 1.f / (float)imax(n0d0, 1);
    const float r10 = 1.f / (float)imax(n1d0, 1);
    const float r01 = 1.f / (float)imax(n0d1, 1);
    const float r11 = 1.f / (float)imax(n1d1, 1);
    float a = 0.f;
    if (t >= WIN && t < TT - WIN) {
      #pragma unroll
      for (int dj = -WIN; dj <= WIN; ++dj) {
        const int j = t + dj;
        const float v = (float)Xsh[j - XLO][((si2 + ((dj >= 0) ? 1 : 0)) << 6) + lane];
        const float w = (dj >= 0) ? (ssp[j] ? r11 : r01) : (ssp[j] ? r10 : r00);
        a = fmaf(w, v, a);
      }
    } else {
      #pragma unroll
      for (int dj = -WIN; dj <= WIN; ++dj) {
        const int j = t + dj;
        const int jc = imin(imax(j, XLO), XLO + 74);
        const float v = (float)Xsh[jc - XLO][((si2 + ((dj >= 0) ? 1 : 0)) << 6) + lane];
        float w = (dj >= 0) ? (ssp[jc] ? r11 : r01) : (ssp[jc] ? r10 : r00);
        if (j < 0 || j >= TT) w = 0.f;
        a = fmaf(w, v, a);
      }
    }
    a += (float)Xsh[t - XLO][256 + lane] + bias;
    h1f[lh][lane] = a;
  }
  __syncthreads();
  for (int lt = w8; lt < 55; lt += 8) {
    const int t = t0 + lt;
    float a = 0.f;
    if (t >= WIN && t < TT - WIN) {
      #pragma unroll
      for (int dj = -WIN; dj <= WIN; ++dj)
        a += h1f[t + dj - H1LO][lane];
    } else {
      #pragma unroll
      for (int dj = -WIN; dj <= WIN; ++dj) {
        const int j = t + dj;
        const int jc = imin(imax(j, H1LO), H1LO + 64);
        const float m = ((j >= 0) && (j < TT)) ? 1.f : 0.f;
        a = fmaf(m, h1f[jc - H1LO][lane], a);
      }
    }
    aggbf[lt][lane] = (__bf16)a;
  }
  __syncthreads();
  if (w8 < 4) {
    const int wm = w8 >> 1, wn = w8 & 1;
    const int fr = lane & 15, fk = (lane >> 4) << 3, row0 = (lane >> 4) << 2;
    const int lhh = t0 - H1LO;
    f32x4 acc[2][2];
    #pragma unroll
    for (int f = 0; f < 2; ++f)
      #pragma unroll
      for (int g = 0; g < 2; ++g) acc[f][g] = (f32x4){0.f,0.f,0.f,0.f};
    #pragma unroll
    for (int kt = 0; kt < 4; ++kt) {
      const int ko = (kt << 5) + fk;
      bf16x8 af[2];
      #pragma unroll
      for (int f = 0; f < 2; ++f) {
        const int tr = wm*32 + f*16 + fr;
        if (tr < 55) {
          if (ko < 64) {
            af[f] = *(const bf16x8*)&aggbf[tr][ko];
          } else {
            const float* src = &h1f[tr + lhh][ko - 64];
            const float4 u0 = ((const float4*)src)[0];
            const float4 u1 = ((const float4*)src)[1];
            af[f] = (bf16x8){(__bf16)u0.x,(__bf16)u0.y,(__bf16)u0.z,(__bf16)u0.w,
                             (__bf16)u1.x,(__bf16)u1.y,(__bf16)u1.z,(__bf16)u1.w};
          }
        } else af[f] = (bf16x8){0,0,0,0,0,0,0,0};
      }
      bf16x8 bfv[2];
      #pragma unroll
      for (int g = 0; g < 2; ++g) {
        const int rb_ = wn*32 + g*16 + fr;
        bfv[g] = *(const bf16x8*)(Wgcimg + rb_*128 + (((ko >> 3) ^ (rb_ & 7)) << 3));
      }
      #pragma unroll
      for (int f = 0; f < 2; ++f)
        #pragma unroll
        for (int g = 0; g < 2; ++g)
          acc[f][g] = __builtin_amdgcn_mfma_f32_16x16x32_bf16(af[f], bfv[g], acc[f][g], 0, 0, 0);
    }
    #pragma unroll
    for (int g = 0; g < 2; ++g) {
      const int col = wn*32 + g*16 + fr;
      const float bv = brel[col];
      #pragma unroll
      for (int f = 0; f < 2; ++f) {
        const int tr0 = wm*32 + f*16 + row0;
        #pragma unroll
        for (int r2 = 0; r2 < 4; ++r2) {
          const int tr = tr0 + r2;
          if (tr < 55) {
            const int t = t0 + tr;
            h2[((size_t)t * BBD + b) * 64 + col] = (__bf16)(acc[f][g][r2] + bv);
          }
        }
      }
    }
  }
}

// ---------------------------------------------------------------------------
// attn_fused: MFMA matching attention + hidden GEMM + logits + log_softmax.
// ---------------------------------------------------------------------------
__global__ __launch_bounds__(448) void attn_fused_k(
    const __bf16* __restrict__ x, const __bf16* __restrict__ h2,
    const __bf16* __restrict__ Xq, const __bf16* __restrict__ Wlimg,
    const float* __restrict__ bl, const float* __restrict__ Wsm,
    const float* __restrict__ bsm, float* __restrict__ out)
{
  __shared__ __align__(16) __bf16 Msh [TT ][272];
  __shared__ __align__(16) __bf16 MTsh[264][136];
  __shared__ __align__(16) __bf16 Ash [112][136];
  const int b = blockIdx.x;
  const int tid = threadIdx.x;

  for (int idx = tid; idx < TT * 66; idx += 448) {
    const int s = idx / 66, c4 = idx % 66;
    const size_t node = (size_t)s * BBD + b;
    bf16x4 pk;
    if (c4 < 50) pk = *(const bf16x4*)&x [node * 200 + (c4 << 2)];
    else         pk = *(const bf16x4*)&h2[node * 64 + ((c4 - 50) << 2)];
    *(bf16x4*)&Msh[s][c4 << 2] = pk;
    const int d = c4 << 2;
    MTsh[d+0][s] = pk[0]; MTsh[d+1][s] = pk[1];
    MTsh[d+2][s] = pk[2]; MTsh[d+3][s] = pk[3];
  }
  for (int idx = tid; idx < 264 * 26; idx += 448) MTsh[idx / 26][110 + idx % 26] = (__bf16)0.f;
  for (int idx = tid; idx < 112 * 24; idx += 448) Ash[idx / 24][112 + idx % 24] = (__bf16)0.f;
  __syncthreads();

  const int wid = tid >> 6, lane = tid & 63;
  const int t0 = wid << 4;
  const int fr = lane & 15;
  const int g  = lane >> 4;
  const int fk = g << 3;
  const int row0 = g << 2;

  f32x4 sacc[7];
  #pragma unroll
  for (int st = 0; st < 7; ++st) sacc[st] = (f32x4){0.f,0.f,0.f,0.f};
  const int trow = t0 + fr;
  const size_t arow = ((size_t)(trow < TT ? trow : TT - 1) * BBD + b) * 264;
  for (int kst = 0; kst < 9; ++kst) {
    const int k0 = kst << 5;
    bf16x8 aq;
    if (kst < 8 || fk == 0) aq = *(const bf16x8*)&Xq[arow + k0 + fk];
    else aq = (bf16x8){0,0,0,0,0,0,0,0};
    #pragma unroll
    for (int st = 0; st < 7; ++st) {
      bf16x8 bq;
      if (kst < 8) bq = *(const bf16x8*)&Msh[st*16 + fr][k0 + fk];
      else bq = (fk == 0) ? *(const bf16x8*)&Msh[st*16 + fr][256]
                          : (bf16x8){0,0,0,0,0,0,0,0};
      sacc[st] = __builtin_amdgcn_mfma_f32_16x16x32_bf16(aq, bq, sacc[st], 0, 0, 0);
    }
  }

  #pragma unroll
  for (int r = 0; r < 4; ++r) {
    float tv[7];
    #pragma unroll
    for (int st = 0; st < 7; ++st) {
      const float e2 = __expf(2.f * sacc[st][r]);
      tv[st] = 1.f - 2.f / (e2 + 1.f);
    }
    if (fr >= 14) tv[6] = -3.0e38f;
    float mx = fmaxf(fmaxf(fmaxf(tv[0],tv[1]), fmaxf(tv[2],tv[3])),
                     fmaxf(fmaxf(tv[4],tv[5]), tv[6]));
    #pragma unroll
    for (int o = 8; o >= 1; o >>= 1) mx = fmaxf(mx, __shfl_xor(mx, o, 16));
    float e[7], sum = 0.f;
    #pragma unroll
    for (int st = 0; st < 7; ++st) { e[st] = __expf(tv[st] - mx); sum += e[st]; }
    #pragma unroll
    for (int o = 8; o >= 1; o >>= 1) sum += __shfl_xor(sum, o, 16);
    const float inv = 1.f / sum;
    const int tr = t0 + (g << 2) + r;
    #pragma unroll
    for (int st = 0; st < 7; ++st) Ash[tr][st*16 + fr] = (__bf16)(e[st] * inv);
  }
  __syncthreads();

  __bf16 (*attsh)[272] = Msh;
  const int tr2 = t0 + (g << 2);
  for (int dt = 0; dt < 17; ++dt) {
    const int d0 = dt << 4;
    f32x4 pacc = (f32x4){0.f,0.f,0.f,0.f};
    #pragma unroll
    for (int kst = 0; kst < 4; ++kst) {
      const int k0 = kst << 5;
      const bf16x8 pa = *(const bf16x8*)&Ash [t0 + fr][k0 + fk];
      const bf16x8 pb = *(const bf16x8*)&MTsh[d0 + fr][k0 + fk];
      pacc = __builtin_amdgcn_mfma_f32_16x16x32_bf16(pa, pb, pacc, 0, 0, 0);
    }
    const int col = d0 + fr;
    if (col < 264) {
      #pragma unroll
      for (int r = 0; r < 4; ++r) {
        const int t = tr2 + r;
        if (t < TT) attsh[t][col] = (__bf16)pacc[r];
      }
    }
  }
  __syncthreads();

  float* Wssh = (float*)&MTsh[0][0];
  for (int i = tid; i < 512; i += 448) {
    const int k = i >> 3, cc = i & 7;
    Wssh[(k << 3) + cc] = (cc < 7) ? Wsm[k*7 + cc] : 0.f;
  }

  float (*hidf)[68] = (float(*)[68])&Ash[0][0];
  f32x4 hacc[4];
  #pragma unroll
  for (int gg = 0; gg < 4; ++gg) hacc[gg] = (f32x4){0.f,0.f,0.f,0.f};
  #pragma unroll
  for (int kst = 0; kst < 9; ++kst) {
    const int ko = (kst << 5) + fk;
    const int ar = t0 + fr;
    bf16x8 af;
    if (ko < 264 && ar < TT) af = *(const bf16x8*)&attsh[ar][ko];
    else af = (bf16x8){0,0,0,0,0,0,0,0};
    #pragma unroll
    for (int gg = 0; gg < 4; ++gg) {
      const int rb_ = gg*16 + fr;
      const bf16x8 bfv = *(const bf16x8*)(Wlimg + rb_*320 + (((ko >> 3) ^ (rb_ & 7)) << 3));
      hacc[gg] = __builtin_amdgcn_mfma_f32_16x16x32_bf16(af, bfv, hacc[gg], 0, 0, 0);
    }
  }
  #pragma unroll
  for (int gg = 0; gg < 4; ++gg) {
    const int col = gg*16 + fr;
    const float bv = bl[col];
    #pragma unroll
    for (int r = 0; r < 4; ++r) {
      const int row = t0 + row0 + r;
      if (row < TT) hidf[row][col] = fmaxf(hacc[gg][r] + bv, 0.f);
    }
  }
  __syncthreads();

  const int c = tid & 7;
  const float bc = (c < 7) ? bsm[c] : 0.f;
  #pragma unroll
  for (int p = 0; p < 2; ++p) {
    const int lr = p * 56 + (tid >> 3);
    if (lr < TT) {
      float lg = -3.0e38f;
      if (c < 7) {
        lg = bc;
        #pragma unroll
        for (int k = 0; k < 64; ++k) lg += hidf[lr][k] * Wssh[(k << 3) + c];
      }
      float mx = lg;
      #pragma unroll
      for (int o = 4; o >= 1; o >>= 1) mx = fmaxf(mx, __shfl_xor(mx, o, 8));
      float e = (c < 7) ? __expf(lg - mx) : 0.f;
      float sm = e;
      #pragma unroll
      for (int o = 4; o >= 1; o >>= 1) sm += __shfl_xor(sm, o, 8);
      if (c < 7) out[((size_t)b * TT + lr) * 7 + c] = lg - mx - __logf(sm);
    }
  }
}

// ---------------------------------------------------------------------------
extern "C" void kernel_launch(void* const* d_in, const int* in_sizes, int n_in,
                              void* d_out, int out_size, void* d_ws, size_t ws_size,
                              hipStream_t stream)
{
  const float* textf  = (const float*)d_in[0];
  const float* acouf  = (const float*)d_in[1];
  const float* visuf  = (const float*)d_in[2];
  const int*   spk    = (const int*)  d_in[3];
  const float* Wf     = (const float*)d_in[4];
  const float* bfv    = (const float*)d_in[5];
  const float* basis  = (const float*)d_in[6];
  const float* comp   = (const float*)d_in[7];
  const float* root   = (const float*)d_in[8];
  const float* brg    = (const float*)d_in[9];
  const float* Wrel   = (const float*)d_in[10];
  const float* brel   = (const float*)d_in[11];
  const float* Wroot2 = (const float*)d_in[12];
  const float* Wma    = (const float*)d_in[13];
  const float* bma    = (const float*)d_in[14];
  const float* Wl     = (const float*)d_in[15];
  const float* bl     = (const float*)d_in[16];
  const float* Wsm    = (const float*)d_in[17];
  const float* bsm    = (const float*)d_in[18];

  float* ws = (float*)d_ws;
  float*  wrels = ws;                               // @0        (115,200 f32)
  __bf16* img   = (__bf16*)(ws + 115200);           // 360,448 bf16 images
  __bf16* xb    = (__bf16*)(ws + 4801024);          // N*200 bf16
  __bf16* xr    = (__bf16*)(ws + 7617024);          // N*576 bf16
  __bf16* h2    = (__bf16*)(ws + 15727104);         // N*64 bf16
  __bf16* Xqb   = (__bf16*)(ws + 16628224);         // N*264 bf16
  float*  outp  = (float*)d_out;

  __bf16* Wfimg  = img;
  __bf16* wrimg  = img + 81920;
  __bf16* Wmaimg = img + 229376;
  __bf16* Wlimg  = img + 331776;
  __bf16* Wgcimg = img + 352256;

  wrels_k<<<450, 256, 0, stream>>>(basis, comp, root, wrels);
  prep_k<<<176, 256, 0, stream>>>(wrels, Wf, Wma, Wl, Wrel, Wroot2, img);
  bgemm0_k<<<1760, 256, 0, stream>>>(textf, acouf, visuf, Wfimg, bfv, xb);
  bgemm_k<1,7,256,9><<<3960, 256, 0, stream>>>(xb, nullptr, wrimg, nullptr, xr, 576, spk);
  dialog_k<<<512, 512, 0, stream>>>(xr, spk, brg, Wgcimg, brel, h2);
  bgemm_k<2,9,320,5><<<2200, 256, 0, stream>>>(xb, h2, Wmaimg, bma, Xqb, 264, nullptr);
  attn_fused_k<<<256, 448, 0, stream>>>(xb, h2, Xqb, Wlimg, bl, Wsm, bsm, outp);
}

// Round 20
// 145.607 us; speedup vs baseline: 1.1171x; 1.1171x over previous
//
#include <hip/hip_runtime.h>

#define TT   110          // max_seq_len
#define BBD  256          // num dialogues
#define NND  28160        // TT*BBD
#define WIN  10

typedef __bf16 bf16x8 __attribute__((ext_vector_type(8)));
typedef __bf16 bf16x4 __attribute__((ext_vector_type(4)));
typedef float  f32x4  __attribute__((ext_vector_type(4)));

__device__ __forceinline__ int imax(int a, int b){ return a > b ? a : b; }
__device__ __forceinline__ int imin(int a, int b){ return a < b ? a : b; }

// All per-node matrices are SOURCE-MAJOR: row m = t*256 + b  (node n = b*110+t).
// Weight images (bf16, pre-swizzled per 64-col tile, row=col, KSP elems):
//   Wfimg [4][64][320] @ img+0
//   wrimg [9][64][256] @ img+81920
//   Wmaimg[5][64][320] @ img+229376
//   Wlimg [1][64][320] @ img+331776
//   Wgcimg[1][64][128] @ img+352256
// Image storage: source k-chunk c (8 bf16) stored at chunk position c^(col&7).

// ---------------------------------------------------------------------------
// K0: Wrels[r][f][h] = sum_nb comp[r][nb]*basis[nb][f][h]  (r<8); Wrels[8]=root
// ---------------------------------------------------------------------------
__global__ __launch_bounds__(256) void wrels_k(
    const float* __restrict__ basis, const float* __restrict__ comp,
    const float* __restrict__ root, float* __restrict__ wrels)
{
  int idx = blockIdx.x * 256 + threadIdx.x;        // 9*12800 = 115200
  if (idx >= 115200) return;
  int r = idx / 12800, fh = idx % 12800;
  float v;
  if (r < 8) {
    v = 0.f;
    #pragma unroll
    for (int nb = 0; nb < 30; ++nb) v += comp[r*30 + nb] * basis[nb*12800 + fh];
  } else {
    v = root[fh];
  }
  wrels[idx] = v;
}

// ---------------------------------------------------------------------------
// prep_k: build all bf16 pre-swizzled weight tile images (wrels precomputed).
// ---------------------------------------------------------------------------
__global__ __launch_bounds__(256) void prep_k(
    const float* __restrict__ wrels, const float* __restrict__ Wf,
    const float* __restrict__ Wma, const float* __restrict__ Wl,
    const float* __restrict__ Wrel, const float* __restrict__ Wroot2,
    __bf16* __restrict__ img)
{
  constexpr int T1 = 10240;              // Wf   4*64*40
  constexpr int T2 = T1 + 18432;         // wrels 9*64*32
  constexpr int T3 = T2 + 12800;         // Wma  5*64*40
  constexpr int T4 = T3 + 2560;          // Wl   64*40
  constexpr int T5 = T4 + 1024;          // Wgc  64*16
  for (int c = blockIdx.x * 256 + threadIdx.x; c < T5; c += gridDim.x * 256) {
    bf16x8 v;
    __bf16* dst;
    if (c < T1) {
      const int r = c;
      const int cb = r / 2560, r2 = r - cb * 2560;
      const int col = r2 / 40, ch = r2 - col * 40;
      const int cs = (ch & ~7) | ((ch ^ col) & 7);
      const int gc = (cb << 6) + col;
      #pragma unroll
      for (int e = 0; e < 8; ++e) {
        const int k = (cs << 3) + e;
        v[e] = (__bf16)((k < 300 && gc < 200) ? Wf[k*200 + gc] : 0.f);
      }
      dst = img + cb * 20480 + col * 320 + (ch << 3);
    } else if (c < T2) {
      const int r = c - T1;
      const int cb = r >> 11, r2 = r & 2047;
      const int col = r2 >> 5, ch = r2 & 31;
      const int cs = (ch & ~7) | ((ch ^ col) & 7);
      #pragma unroll
      for (int e = 0; e < 8; ++e) {
        const int k = (cs << 3) + e;
        v[e] = (__bf16)((k < 200) ? wrels[cb*12800 + k*64 + col] : 0.f);
      }
      dst = img + 81920 + cb * 16384 + col * 256 + (ch << 3);
    } else if (c < T3) {
      const int r = c - T2;
      const int cb = r / 2560, r2 = r - cb * 2560;
      const int col = r2 / 40, ch = r2 - col * 40;
      const int cs = (ch & ~7) | ((ch ^ col) & 7);
      const int gc = (cb << 6) + col;
      #pragma unroll
      for (int e = 0; e < 8; ++e) {
        const int k = (cs << 3) + e;
        v[e] = (__bf16)((k < 264 && gc < 264) ? Wma[k*264 + gc] : 0.f);
      }
      dst = img + 229376 + cb * 20480 + col * 320 + (ch << 3);
    } else if (c < T4) {
      const int r = c - T3;
      const int col = r / 40, ch = r - col * 40;
      const int cs = (ch & ~7) | ((ch ^ col) & 7);
      #pragma unroll
      for (int e = 0; e < 8; ++e) {
        const int k = (cs << 3) + e;
        v[e] = (__bf16)((k < 264) ? Wl[k*64 + col] : 0.f);
      }
      dst = img + 331776 + col * 320 + (ch << 3);
    } else {
      const int r = c - T4;
      const int col = r / 16, ch = r - col * 16;
      const int cs = (ch & ~7) | ((ch ^ col) & 7);
      #pragma unroll
      for (int e = 0; e < 8; ++e) {
        const int k = (cs << 3) + e;
        v[e] = (__bf16)((k < 64) ? Wrel[k*64 + col] : Wroot2[(k-64)*64 + col]);
      }
      dst = img + 352256 + col * 128 + (ch << 3);
    }
    *(bf16x8*)dst = v;
  }
}

// ---------------------------------------------------------------------------
// bgemm0_k (round 20): A staged to LDS (40 KB only -> 4 blocks/CU);
// B fragments read DIRECTLY from the L2-resident pre-swizzled image.
// ---------------------------------------------------------------------------
__global__ __launch_bounds__(256) void bgemm0_k(
    const float* __restrict__ a0, const float* __restrict__ a1,
    const float* __restrict__ a2, const __bf16* __restrict__ Bimg,
    const float* __restrict__ bias, __bf16* __restrict__ Cv)
{
  __shared__ __align__(16) __bf16 Ash[64][320];
  const int tid = threadIdx.x;
  constexpr int NWT = 1760, q = NWT >> 3;
  const int bid = blockIdx.x;
  const int w = (bid & 7) * q + (bid >> 3);
  const int m0 = (w >> 2) << 6;
  const int cb = w & 3;
  const int n0 = cb << 6;
  const __bf16* Bt = Bimg + (size_t)cb * (64 * 320);

  { // ---- stage A: coalesced f32 -> bf16, swizzled chunks ----
    #pragma unroll
    for (int it = 0; it < 10; ++it) {
      const int i = it * 256 + tid;
      const int row = i / 40, ch = i - row * 40;
      const int cs = (ch & ~7) | ((ch ^ row) & 7);
      const size_t ab = (size_t)(m0 + row) * 100;
      float4 u[2];
      #pragma unroll
      for (int h = 0; h < 2; ++h) {
        const int g4 = (cs << 3) + (h << 2);
        if (g4 < 100)      u[h] = *(const float4*)(a0 + ab + g4);
        else if (g4 < 200) u[h] = *(const float4*)(a1 + ab + g4 - 100);
        else if (g4 < 300) u[h] = *(const float4*)(a2 + ab + g4 - 200);
        else               u[h] = make_float4(0.f,0.f,0.f,0.f);
      }
      *(bf16x8*)&Ash[row][ch << 3] =
        (bf16x8){(__bf16)u[0].x,(__bf16)u[0].y,(__bf16)u[0].z,(__bf16)u[0].w,
                 (__bf16)u[1].x,(__bf16)u[1].y,(__bf16)u[1].z,(__bf16)u[1].w};
    }
  }
  __syncthreads();

  const int wid = tid >> 6, lane = tid & 63;
  const int wm = wid >> 1, wn = wid & 1;
  const int fr = lane & 15;
  const int fk = (lane >> 4) << 3;
  const int row0 = (lane >> 4) << 2;

  f32x4 acc[2][2];
  #pragma unroll
  for (int f = 0; f < 2; ++f)
    #pragma unroll
    for (int g = 0; g < 2; ++g) acc[f][g] = (f32x4){0.f,0.f,0.f,0.f};

  #pragma unroll
  for (int kt = 0; kt < 10; ++kt) {
    const int ko = (kt << 5) + fk;
    bf16x8 af[2], bfv[2];
    #pragma unroll
    for (int f = 0; f < 2; ++f) {
      const int ra = wm*32 + f*16 + fr;
      af[f] = *(const bf16x8*)&Ash[ra][(((ko >> 3) ^ (ra & 7)) << 3)];
    }
    #pragma unroll
    for (int g = 0; g < 2; ++g) {
      const int rb_ = wn*32 + g*16 + fr;
      bfv[g] = *(const bf16x8*)(Bt + rb_*320 + (((ko >> 3) ^ (rb_ & 7)) << 3));
    }
    #pragma unroll
    for (int f = 0; f < 2; ++f)
      #pragma unroll
      for (int g = 0; g < 2; ++g)
        acc[f][g] = __builtin_amdgcn_mfma_f32_16x16x32_bf16(af[f], bfv[g], acc[f][g], 0, 0, 0);
  }

  #pragma unroll
  for (int f = 0; f < 2; ++f) {
    const int gm0 = m0 + wm*32 + f*16 + row0;
    #pragma unroll
    for (int g = 0; g < 2; ++g) {
      const int col = n0 + wn*32 + g*16 + fr;
      if (col < 200) {
        const float bv = bias[col];
        #pragma unroll
        for (int r2 = 0; r2 < 4; ++r2)
          Cv[(size_t)(gm0 + r2) * 200 + col] = (__bf16)(acc[f][g][r2] + bv);
      }
    }
  }
}

// ---------------------------------------------------------------------------
// bgemm: B-resident MFMA GEMM, pre-swizzled B image (modes 1, 2).
// ---------------------------------------------------------------------------
template<int MODE, int NK, int KSP, int NCB>
__global__ __launch_bounds__(256) void bgemm_k(
    const void* __restrict__ a0, const void* __restrict__ a1,
    const __bf16* __restrict__ Bimg, const float* __restrict__ bias,
    __bf16* __restrict__ Cv, int Ncols, const int* __restrict__ spkm)
{
  __shared__ __align__(16) __bf16 Bsh[64][KSP];
  const int tid = threadIdx.x;
  constexpr int NWT = 440 * NCB;
  constexpr int q = NWT >> 3;
  const int bid = blockIdx.x;
  const int w = (bid & 7) * q + (bid >> 3);
  const int m0 = (w / NCB) << 6;
  const int cb = w % NCB;
  const int n0 = cb << 6;

  {
    const bf16x8* src = (const bf16x8*)(Bimg + (size_t)cb * (64 * KSP));
    bf16x8* dst = (bf16x8*)&Bsh[0][0];
    constexpr int NIT = (64 * KSP / 8) / 256;
    #pragma unroll
    for (int c = 0; c < NIT; ++c) dst[c * 256 + tid] = src[c * 256 + tid];
  }
  __syncthreads();

  const int wid = tid >> 6, lane = tid & 63;
  const int wm = wid >> 1, wn = wid & 1;
  const int fr = lane & 15;
  const int fk = (lane >> 4) << 3;
  const int row0 = (lane >> 4) << 2;

  f32x4 acc[2][2];
  #pragma unroll
  for (int f = 0; f < 2; ++f)
    #pragma unroll
    for (int g = 0; g < 2; ++g) acc[f][g] = (f32x4){0.f,0.f,0.f,0.f};

  #pragma unroll
  for (int kt = 0; kt < NK; ++kt) {
    const int ko = (kt << 5) + fk;
    bf16x8 af[2];
    #pragma unroll
    for (int f = 0; f < 2; ++f) {
      const int ra = m0 + wm*32 + f*16 + fr;
      if constexpr (MODE == 2) {
        af[f] = (ko < 200)
              ? *(const bf16x8*)((const __bf16*)a0 + (size_t)ra*200 + ko)
              : *(const bf16x8*)((const __bf16*)a1 + (size_t)ra*64 + (ko - 200));
      } else {
        af[f] = *(const bf16x8*)((const __bf16*)a0 + (size_t)ra*200 + ko);
      }
    }
    bf16x8 bfv[2];
    #pragma unroll
    for (int g = 0; g < 2; ++g) {
      const int rb_ = wn*32 + g*16 + fr;
      bfv[g] = *(const bf16x8*)&Bsh[rb_][(((ko >> 3) ^ (rb_ & 7)) << 3)];
    }
    #pragma unroll
    for (int f = 0; f < 2; ++f)
      #pragma unroll
      for (int g = 0; g < 2; ++g)
        acc[f][g] = __builtin_amdgcn_mfma_f32_16x16x32_bf16(af[f], bfv[g], acc[f][g], 0, 0, 0);
  }

  #pragma unroll
  for (int f = 0; f < 2; ++f) {
    const int gm0 = m0 + wm*32 + f*16 + row0;
    int sp[4];
    if constexpr (MODE == 1) {
      #pragma unroll
      for (int r2 = 0; r2 < 4; ++r2) sp[r2] = spkm[gm0 + r2];
    }
    #pragma unroll
    for (int g = 0; g < 2; ++g) {
      const int col = n0 + wn*32 + g*16 + fr;
      if (col < Ncols) {
        const float bv = bias ? bias[col] : 0.f;
        #pragma unroll
        for (int r2 = 0; r2 < 4; ++r2) {
          const float v = acc[f][g][r2] + bv;
          const int gm = gm0 + r2;
          bool dow = true;
          if constexpr (MODE == 1) dow = (cb == 8) || ((cb >> 2) == sp[r2]);
          if (dow) Cv[(size_t)gm * Ncols + col] = (__bf16)v;
        }
      }
    }
  }
}

// ---------------------------------------------------------------------------
// dialog_k: fused RGCN mean-agg + window-sum + GraphConv GEMM (round-14 cfg).
// ---------------------------------------------------------------------------
__global__ __launch_bounds__(512) void dialog_k(
    const __bf16* __restrict__ xr, const int* __restrict__ spk,
    const float* __restrict__ brg, const __bf16* __restrict__ Wgcimg,
    const float* __restrict__ brel, __bf16* __restrict__ h2)
{
  __shared__ __align__(16) __bf16 Xsh[75][320];
  __shared__ float  h1f[65][68];
  __shared__ __align__(16) __bf16 aggbf[56][72];
  __shared__ int ssp[TT];
  __shared__ int pc[TT + 1];
  const int bid = blockIdx.x;
  const int b = bid >> 1, half = bid & 1;
  const int t0   = half ? 55 : 0;
  const int H1LO = half ? 45 : 0;
  const int XLO  = half ? 35 : 0;
  const int tid = threadIdx.x;
  if (tid < TT) ssp[tid] = spk[tid * BBD + b];
  __syncthreads();
  if (tid < 64) {
    int v = (tid < TT) ? ssp[tid] : 0;
    #pragma unroll
    for (int o = 1; o < 64; o <<= 1) { const int u = __shfl_up(v, o); if (tid >= o) v += u; }
    pc[tid + 1] = v;
    const int tot = __shfl(v, 63);
    int v2 = (tid + 64 < TT) ? ssp[tid + 64] : 0;
    #pragma unroll
    for (int o = 1; o < 64; o <<= 1) { const int u = __shfl_up(v2, o); if (tid >= o) v2 += u; }
    if (tid + 64 < TT) pc[tid + 65] = tot + v2;
    if (tid == 0) pc[0] = 0;
  }
  for (int i = tid << 3; i < 75 * 320; i += 512 << 3) {
    const int xl = i / 320, off = i - xl * 320;
    const int j = XLO + xl;
    const size_t base = ((size_t)j * BBD + b) * 576;
    const int col = (off < 256) ? ((ssp[j] << 8) + off) : (256 + off);
    *(bf16x8*)&Xsh[xl][off] = *(const bf16x8*)&xr[base + col];
  }
  __syncthreads();
  const int w8 = tid >> 6, lane = tid & 63;
  const float bias = brg[lane];
  for (int lh = w8; lh < 65; lh += 8) {
    const int t = H1LO + lh;
    const int si2 = ssp[t] << 1;
    const int jlo = imax(t - WIN, 0), jhi = imin(t + WIN, TT - 1);
    const int n1d0 = pc[t] - pc[jlo];
    const int n0d0 = (t - jlo) - n1d0;
    const int n1d1 = pc[jhi + 1] - pc[t];
    const int n0d1 = (jhi - t + 1) - n1d1;
    const float r00 = 1.f / (float)imax(n0d0, 1);
    const float r10 = 1.f / (float)imax(n1d0, 1);
    const float r01 = 1.f / (float)imax(n0d1, 1);
    const float r11 = 1.f / (float)imax(n1d1, 1);
    float a = 0.f;
    if (t >= WIN && t < TT - WIN) {
      #pragma unroll
      for (int dj = -WIN; dj <= WIN; ++dj) {
        const int j = t + dj;
        const float v = (float)Xsh[j - XLO][((si2 + ((dj >= 0) ? 1 : 0)) << 6) + lane];
        const float w = (dj >= 0) ? (ssp[j] ? r11 : r01) : (ssp[j] ? r10 : r00);
        a = fmaf(w, v, a);
      }
    } else {
      #pragma unroll
      for (int dj = -WIN; dj <= WIN; ++dj) {
        const int j = t + dj;
        const int jc = imin(imax(j, XLO), XLO + 74);
        const float v = (float)Xsh[jc - XLO][((si2 + ((dj >= 0) ? 1 : 0)) << 6) + lane];
        float w = (dj >= 0) ? (ssp[jc] ? r11 : r01) : (ssp[jc] ? r10 : r00);
        if (j < 0 || j >= TT) w = 0.f;
        a = fmaf(w, v, a);
      }
    }
    a += (float)Xsh[t - XLO][256 + lane] + bias;
    h1f[lh][lane] = a;
  }
  __syncthreads();
  for (int lt = w8; lt < 55; lt += 8) {
    const int t = t0 + lt;
    float a = 0.f;
    if (t >= WIN && t < TT - WIN) {
      #pragma unroll
      for (int dj = -WIN; dj <= WIN; ++dj)
        a += h1f[t + dj - H1LO][lane];
    } else {
      #pragma unroll
      for (int dj = -WIN; dj <= WIN; ++dj) {
        const int j = t + dj;
        const int jc = imin(imax(j, H1LO), H1LO + 64);
        const float m = ((j >= 0) && (j < TT)) ? 1.f : 0.f;
        a = fmaf(m, h1f[jc - H1LO][lane], a);
      }
    }
    aggbf[lt][lane] = (__bf16)a;
  }
  __syncthreads();
  if (w8 < 4) {
    const int wm = w8 >> 1, wn = w8 & 1;
    const int fr = lane & 15, fk = (lane >> 4) << 3, row0 = (lane >> 4) << 2;
    const int lhh = t0 - H1LO;
    f32x4 acc[2][2];
    #pragma unroll
    for (int f = 0; f < 2; ++f)
      #pragma unroll
      for (int g = 0; g < 2; ++g) acc[f][g] = (f32x4){0.f,0.f,0.f,0.f};
    #pragma unroll
    for (int kt = 0; kt < 4; ++kt) {
      const int ko = (kt << 5) + fk;
      bf16x8 af[2];
      #pragma unroll
      for (int f = 0; f < 2; ++f) {
        const int tr = wm*32 + f*16 + fr;
        if (tr < 55) {
          if (ko < 64) {
            af[f] = *(const bf16x8*)&aggbf[tr][ko];
          } else {
            const float* src = &h1f[tr + lhh][ko - 64];
            const float4 u0 = ((const float4*)src)[0];
            const float4 u1 = ((const float4*)src)[1];
            af[f] = (bf16x8){(__bf16)u0.x,(__bf16)u0.y,(__bf16)u0.z,(__bf16)u0.w,
                             (__bf16)u1.x,(__bf16)u1.y,(__bf16)u1.z,(__bf16)u1.w};
          }
        } else af[f] = (bf16x8){0,0,0,0,0,0,0,0};
      }
      bf16x8 bfv[2];
      #pragma unroll
      for (int g = 0; g < 2; ++g) {
        const int rb_ = wn*32 + g*16 + fr;
        bfv[g] = *(const bf16x8*)(Wgcimg + rb_*128 + (((ko >> 3) ^ (rb_ & 7)) << 3));
      }
      #pragma unroll
      for (int f = 0; f < 2; ++f)
        #pragma unroll
        for (int g = 0; g < 2; ++g)
          acc[f][g] = __builtin_amdgcn_mfma_f32_16x16x32_bf16(af[f], bfv[g], acc[f][g], 0, 0, 0);
    }
    #pragma unroll
    for (int g = 0; g < 2; ++g) {
      const int col = wn*32 + g*16 + fr;
      const float bv = brel[col];
      #pragma unroll
      for (int f = 0; f < 2; ++f) {
        const int tr0 = wm*32 + f*16 + row0;
        #pragma unroll
        for (int r2 = 0; r2 < 4; ++r2) {
          const int tr = tr0 + r2;
          if (tr < 55) {
            const int t = t0 + tr;
            h2[((size_t)t * BBD + b) * 64 + col] = (__bf16)(acc[f][g][r2] + bv);
          }
        }
      }
    }
  }
}

// ---------------------------------------------------------------------------
// attn_fused: MFMA matching attention + hidden GEMM + logits + log_softmax.
// ---------------------------------------------------------------------------
__global__ __launch_bounds__(448) void attn_fused_k(
    const __bf16* __restrict__ x, const __bf16* __restrict__ h2,
    const __bf16* __restrict__ Xq, const __bf16* __restrict__ Wlimg,
    const float* __restrict__ bl, const float* __restrict__ Wsm,
    const float* __restrict__ bsm, float* __restrict__ out)
{
  __shared__ __align__(16) __bf16 Msh [TT ][272];
  __shared__ __align__(16) __bf16 MTsh[264][136];
  __shared__ __align__(16) __bf16 Ash [112][136];
  const int b = blockIdx.x;
  const int tid = threadIdx.x;

  for (int idx = tid; idx < TT * 66; idx += 448) {
    const int s = idx / 66, c4 = idx % 66;
    const size_t node = (size_t)s * BBD + b;
    bf16x4 pk;
    if (c4 < 50) pk = *(const bf16x4*)&x [node * 200 + (c4 << 2)];
    else         pk = *(const bf16x4*)&h2[node * 64 + ((c4 - 50) << 2)];
    *(bf16x4*)&Msh[s][c4 << 2] = pk;
    const int d = c4 << 2;
    MTsh[d+0][s] = pk[0]; MTsh[d+1][s] = pk[1];
    MTsh[d+2][s] = pk[2]; MTsh[d+3][s] = pk[3];
  }
  for (int idx = tid; idx < 264 * 26; idx += 448) MTsh[idx / 26][110 + idx % 26] = (__bf16)0.f;
  for (int idx = tid; idx < 112 * 24; idx += 448) Ash[idx / 24][112 + idx % 24] = (__bf16)0.f;
  __syncthreads();

  const int wid = tid >> 6, lane = tid & 63;
  const int t0 = wid << 4;
  const int fr = lane & 15;
  const int g  = lane >> 4;
  const int fk = g << 3;
  const int row0 = g << 2;

  f32x4 sacc[7];
  #pragma unroll
  for (int st = 0; st < 7; ++st) sacc[st] = (f32x4){0.f,0.f,0.f,0.f};
  const int trow = t0 + fr;
  const size_t arow = ((size_t)(trow < TT ? trow : TT - 1) * BBD + b) * 264;
  for (int kst = 0; kst < 9; ++kst) {
    const int k0 = kst << 5;
    bf16x8 aq;
    if (kst < 8 || fk == 0) aq = *(const bf16x8*)&Xq[arow + k0 + fk];
    else aq = (bf16x8){0,0,0,0,0,0,0,0};
    #pragma unroll
    for (int st = 0; st < 7; ++st) {
      bf16x8 bq;
      if (kst < 8) bq = *(const bf16x8*)&Msh[st*16 + fr][k0 + fk];
      else bq = (fk == 0) ? *(const bf16x8*)&Msh[st*16 + fr][256]
                          : (bf16x8){0,0,0,0,0,0,0,0};
      sacc[st] = __builtin_amdgcn_mfma_f32_16x16x32_bf16(aq, bq, sacc[st], 0, 0, 0);
    }
  }

  #pragma unroll
  for (int r = 0; r < 4; ++r) {
    float tv[7];
    #pragma unroll
    for (int st = 0; st < 7; ++st) {
      const float e2 = __expf(2.f * sacc[st][r]);
      tv[st] = 1.f - 2.f / (e2 + 1.f);
    }
    if (fr >= 14) tv[6] = -3.0e38f;
    float mx = fmaxf(fmaxf(fmaxf(tv[0],tv[1]), fmaxf(tv[2],tv[3])),
                     fmaxf(fmaxf(tv[4],tv[5]), tv[6]));
    #pragma unroll
    for (int o = 8; o >= 1; o >>= 1) mx = fmaxf(mx, __shfl_xor(mx, o, 16));
    float e[7], sum = 0.f;
    #pragma unroll
    for (int st = 0; st < 7; ++st) { e[st] = __expf(tv[st] - mx); sum += e[st]; }
    #pragma unroll
    for (int o = 8; o >= 1; o >>= 1) sum += __shfl_xor(sum, o, 16);
    const float inv = 1.f / sum;
    const int tr = t0 + (g << 2) + r;
    #pragma unroll
    for (int st = 0; st < 7; ++st) Ash[tr][st*16 + fr] = (__bf16)(e[st] * inv);
  }
  __syncthreads();

  __bf16 (*attsh)[272] = Msh;
  const int tr2 = t0 + (g << 2);
  for (int dt = 0; dt < 17; ++dt) {
    const int d0 = dt << 4;
    f32x4 pacc = (f32x4){0.f,0.f,0.f,0.f};
    #pragma unroll
    for (int kst = 0; kst < 4; ++kst) {
      const int k0 = kst << 5;
      const bf16x8 pa = *(const bf16x8*)&Ash [t0 + fr][k0 + fk];
      const bf16x8 pb = *(const bf16x8*)&MTsh[d0 + fr][k0 + fk];
      pacc = __builtin_amdgcn_mfma_f32_16x16x32_bf16(pa, pb, pacc, 0, 0, 0);
    }
    const int col = d0 + fr;
    if (col < 264) {
      #pragma unroll
      for (int r = 0; r < 4; ++r) {
        const int t = tr2 + r;
        if (t < TT) attsh[t][col] = (__bf16)pacc[r];
      }
    }
  }
  __syncthreads();

  float* Wssh = (float*)&MTsh[0][0];
  for (int i = tid; i < 512; i += 448) {
    const int k = i >> 3, cc = i & 7;
    Wssh[(k << 3) + cc] = (cc < 7) ? Wsm[k*7 + cc] : 0.f;
  }

  float (*hidf)[68] = (float(*)[68])&Ash[0][0];
  f32x4 hacc[4];
  #pragma unroll
  for (int gg = 0; gg < 4; ++gg) hacc[gg] = (f32x4){0.f,0.f,0.f,0.f};
  #pragma unroll
  for (int kst = 0; kst < 9; ++kst) {
    const int ko = (kst << 5) + fk;
    const int ar = t0 + fr;
    bf16x8 af;
    if (ko < 264 && ar < TT) af = *(const bf16x8*)&attsh[ar][ko];
    else af = (bf16x8){0,0,0,0,0,0,0,0};
    #pragma unroll
    for (int gg = 0; gg < 4; ++gg) {
      const int rb_ = gg*16 + fr;
      const bf16x8 bfv = *(const bf16x8*)(Wlimg + rb_*320 + (((ko >> 3) ^ (rb_ & 7)) << 3));
      hacc[gg] = __builtin_amdgcn_mfma_f32_16x16x32_bf16(af, bfv, hacc[gg], 0, 0, 0);
    }
  }
  #pragma unroll
  for (int gg = 0; gg < 4; ++gg) {
    const int col = gg*16 + fr;
    const float bv = bl[col];
    #pragma unroll
    for (int r = 0; r < 4; ++r) {
      const int row = t0 + row0 + r;
      if (row < TT) hidf[row][col] = fmaxf(hacc[gg][r] + bv, 0.f);
    }
  }
  __syncthreads();

  const int c = tid & 7;
  const float bc = (c < 7) ? bsm[c] : 0.f;
  #pragma unroll
  for (int p = 0; p < 2; ++p) {
    const int lr = p * 56 + (tid >> 3);
    if (lr < TT) {
      float lg = -3.0e38f;
      if (c < 7) {
        lg = bc;
        #pragma unroll
        for (int k = 0; k < 64; ++k) lg += hidf[lr][k] * Wssh[(k << 3) + c];
      }
      float mx = lg;
      #pragma unroll
      for (int o = 4; o >= 1; o >>= 1) mx = fmaxf(mx, __shfl_xor(mx, o, 8));
      float e = (c < 7) ? __expf(lg - mx) : 0.f;
      float sm = e;
      #pragma unroll
      for (int o = 4; o >= 1; o >>= 1) sm += __shfl_xor(sm, o, 8);
      if (c < 7) out[((size_t)b * TT + lr) * 7 + c] = lg - mx - __logf(sm);
    }
  }
}

// ---------------------------------------------------------------------------
extern "C" void kernel_launch(void* const* d_in, const int* in_sizes, int n_in,
                              void* d_out, int out_size, void* d_ws, size_t ws_size,
                              hipStream_t stream)
{
  const float* textf  = (const float*)d_in[0];
  const float* acouf  = (const float*)d_in[1];
  const float* visuf  = (const float*)d_in[2];
  const int*   spk    = (const int*)  d_in[3];
  const float* Wf     = (const float*)d_in[4];
  const float* bfv    = (const float*)d_in[5];
  const float* basis  = (const float*)d_in[6];
  const float* comp   = (const float*)d_in[7];
  const float* root   = (const float*)d_in[8];
  const float* brg    = (const float*)d_in[9];
  const float* Wrel   = (const float*)d_in[10];
  const float* brel   = (const float*)d_in[11];
  const float* Wroot2 = (const float*)d_in[12];
  const float* Wma    = (const float*)d_in[13];
  const float* bma    = (const float*)d_in[14];
  const float* Wl     = (const float*)d_in[15];
  const float* bl     = (const float*)d_in[16];
  const float* Wsm    = (const float*)d_in[17];
  const float* bsm    = (const float*)d_in[18];

  float* ws = (float*)d_ws;
  float*  wrels = ws;                               // @0        (115,200 f32)
  __bf16* img   = (__bf16*)(ws + 115200);           // 360,448 bf16 images
  __bf16* xb    = (__bf16*)(ws + 4801024);          // N*200 bf16
  __bf16* xr    = (__bf16*)(ws + 7617024);          // N*576 bf16
  __bf16* h2    = (__bf16*)(ws + 15727104);         // N*64 bf16
  __bf16* Xqb   = (__bf16*)(ws + 16628224);         // N*264 bf16
  float*  outp  = (float*)d_out;

  __bf16* Wfimg  = img;
  __bf16* wrimg  = img + 81920;
  __bf16* Wmaimg = img + 229376;
  __bf16* Wlimg  = img + 331776;
  __bf16* Wgcimg = img + 352256;

  wrels_k<<<450, 256, 0, stream>>>(basis, comp, root, wrels);
  prep_k<<<176, 256, 0, stream>>>(wrels, Wf, Wma, Wl, Wrel, Wroot2, img);
  bgemm0_k<<<1760, 256, 0, stream>>>(textf, acouf, visuf, Wfimg, bfv, xb);
  bgemm_k<1,7,256,9><<<3960, 256, 0, stream>>>(xb, nullptr, wrimg, nullptr, xr, 576, spk);
  dialog_k<<<512, 512, 0, stream>>>(xr, spk, brg, Wgcimg, brel, h2);
  bgemm_k<2,9,320,5><<<2200, 256, 0, stream>>>(xb, h2, Wmaimg, bma, Xqb, 264, nullptr);
  attn_fused_k<<<256, 448, 0, stream>>>(xb, h2, Xqb, Wlimg, bl, Wsm, bsm, outp);
}

// Round 21
// 129.382 us; speedup vs baseline: 1.2572x; 1.1254x over previous
//
#include <hip/hip_runtime.h>

#define TT   110          // max_seq_len
#define BBD  256          // num dialogues
#define NND  28160        // TT*BBD
#define WIN  10

typedef __bf16 bf16x8 __attribute__((ext_vector_type(8)));
typedef __bf16 bf16x4 __attribute__((ext_vector_type(4)));
typedef float  f32x4  __attribute__((ext_vector_type(4)));

__device__ __forceinline__ int imax(int a, int b){ return a > b ? a : b; }
__device__ __forceinline__ int imin(int a, int b){ return a < b ? a : b; }

// All per-node matrices are SOURCE-MAJOR: row m = t*256 + b  (node n = b*110+t).
// Weight images (bf16, pre-swizzled per 64-col tile, row=col, KSP elems):
//   Wfimg [4][64][320] @ img+0
//   wrimg [9][64][256] @ img+81920
//   Wmaimg[5][64][320] @ img+229376
//   Wlimg [1][64][320] @ img+331776
//   Wgcimg[1][64][128] @ img+352256
// Image storage: source k-chunk c (8 bf16) stored at chunk position c^(col&7).

// ---------------------------------------------------------------------------
// K0: Wrels[r][f][h] = sum_nb comp[r][nb]*basis[nb][f][h]  (r<8); Wrels[8]=root
// ---------------------------------------------------------------------------
__global__ __launch_bounds__(256) void wrels_k(
    const float* __restrict__ basis, const float* __restrict__ comp,
    const float* __restrict__ root, float* __restrict__ wrels)
{
  int idx = blockIdx.x * 256 + threadIdx.x;        // 9*12800 = 115200
  if (idx >= 115200) return;
  int r = idx / 12800, fh = idx % 12800;
  float v;
  if (r < 8) {
    v = 0.f;
    #pragma unroll
    for (int nb = 0; nb < 30; ++nb) v += comp[r*30 + nb] * basis[nb*12800 + fh];
  } else {
    v = root[fh];
  }
  wrels[idx] = v;
}

// ---------------------------------------------------------------------------
// prep_k: build all bf16 pre-swizzled weight tile images (wrels precomputed).
// ---------------------------------------------------------------------------
__global__ __launch_bounds__(256) void prep_k(
    const float* __restrict__ wrels, const float* __restrict__ Wf,
    const float* __restrict__ Wma, const float* __restrict__ Wl,
    const float* __restrict__ Wrel, const float* __restrict__ Wroot2,
    __bf16* __restrict__ img)
{
  constexpr int T1 = 10240;              // Wf   4*64*40
  constexpr int T2 = T1 + 18432;         // wrels 9*64*32
  constexpr int T3 = T2 + 12800;         // Wma  5*64*40
  constexpr int T4 = T3 + 2560;          // Wl   64*40
  constexpr int T5 = T4 + 1024;          // Wgc  64*16
  for (int c = blockIdx.x * 256 + threadIdx.x; c < T5; c += gridDim.x * 256) {
    bf16x8 v;
    __bf16* dst;
    if (c < T1) {
      const int r = c;
      const int cb = r / 2560, r2 = r - cb * 2560;
      const int col = r2 / 40, ch = r2 - col * 40;
      const int cs = (ch & ~7) | ((ch ^ col) & 7);
      const int gc = (cb << 6) + col;
      #pragma unroll
      for (int e = 0; e < 8; ++e) {
        const int k = (cs << 3) + e;
        v[e] = (__bf16)((k < 300 && gc < 200) ? Wf[k*200 + gc] : 0.f);
      }
      dst = img + cb * 20480 + col * 320 + (ch << 3);
    } else if (c < T2) {
      const int r = c - T1;
      const int cb = r >> 11, r2 = r & 2047;
      const int col = r2 >> 5, ch = r2 & 31;
      const int cs = (ch & ~7) | ((ch ^ col) & 7);
      #pragma unroll
      for (int e = 0; e < 8; ++e) {
        const int k = (cs << 3) + e;
        v[e] = (__bf16)((k < 200) ? wrels[cb*12800 + k*64 + col] : 0.f);
      }
      dst = img + 81920 + cb * 16384 + col * 256 + (ch << 3);
    } else if (c < T3) {
      const int r = c - T2;
      const int cb = r / 2560, r2 = r - cb * 2560;
      const int col = r2 / 40, ch = r2 - col * 40;
      const int cs = (ch & ~7) | ((ch ^ col) & 7);
      const int gc = (cb << 6) + col;
      #pragma unroll
      for (int e = 0; e < 8; ++e) {
        const int k = (cs << 3) + e;
        v[e] = (__bf16)((k < 264 && gc < 264) ? Wma[k*264 + gc] : 0.f);
      }
      dst = img + 229376 + cb * 20480 + col * 320 + (ch << 3);
    } else if (c < T4) {
      const int r = c - T3;
      const int col = r / 40, ch = r - col * 40;
      const int cs = (ch & ~7) | ((ch ^ col) & 7);
      #pragma unroll
      for (int e = 0; e < 8; ++e) {
        const int k = (cs << 3) + e;
        v[e] = (__bf16)((k < 264) ? Wl[k*64 + col] : 0.f);
      }
      dst = img + 331776 + col * 320 + (ch << 3);
    } else {
      const int r = c - T4;
      const int col = r / 16, ch = r - col * 16;
      const int cs = (ch & ~7) | ((ch ^ col) & 7);
      #pragma unroll
      for (int e = 0; e < 8; ++e) {
        const int k = (cs << 3) + e;
        v[e] = (__bf16)((k < 64) ? Wrel[k*64 + col] : Wroot2[(k-64)*64 + col]);
      }
      dst = img + 352256 + col * 128 + (ch << 3);
    }
    *(bf16x8*)dst = v;
  }
}

// ---------------------------------------------------------------------------
// bgemm0_k (round 21): ONE block per 64-row m-tile (grid 440, 512 thr/8 waves).
// A staged ONCE (40 KB, coalesced f32->bf16 swizzled); B direct from L2-hot
// image; 8 waves = 2M x 4N cover 64x128 per column-half, loop 2 halves with
// NO barriers after the stage. A fetched from HBM exactly once.
// ---------------------------------------------------------------------------
__global__ __launch_bounds__(512) void bgemm0_k(
    const float* __restrict__ a0, const float* __restrict__ a1,
    const float* __restrict__ a2, const __bf16* __restrict__ Bimg,
    const float* __restrict__ bias, __bf16* __restrict__ Cv)
{
  __shared__ __align__(16) __bf16 Ash[64][320];
  const int tid = threadIdx.x;
  const int bid = blockIdx.x;
  const int w = (bid & 7) * 55 + (bid >> 3);     // 440 = 8*55, bijective
  const int m0 = w << 6;

  { // ---- stage A: coalesced f32 -> bf16, swizzled chunks (5 iters) ----
    #pragma unroll
    for (int it = 0; it < 5; ++it) {
      const int i = it * 512 + tid;
      const int row = i / 40, ch = i - row * 40;
      const int cs = (ch & ~7) | ((ch ^ row) & 7);
      const size_t ab = (size_t)(m0 + row) * 100;
      float4 u[2];
      #pragma unroll
      for (int h = 0; h < 2; ++h) {
        const int g4 = (cs << 3) + (h << 2);
        if (g4 < 100)      u[h] = *(const float4*)(a0 + ab + g4);
        else if (g4 < 200) u[h] = *(const float4*)(a1 + ab + g4 - 100);
        else if (g4 < 300) u[h] = *(const float4*)(a2 + ab + g4 - 200);
        else               u[h] = make_float4(0.f,0.f,0.f,0.f);
      }
      *(bf16x8*)&Ash[row][ch << 3] =
        (bf16x8){(__bf16)u[0].x,(__bf16)u[0].y,(__bf16)u[0].z,(__bf16)u[0].w,
                 (__bf16)u[1].x,(__bf16)u[1].y,(__bf16)u[1].z,(__bf16)u[1].w};
    }
  }
  __syncthreads();

  const int wid = tid >> 6, lane = tid & 63;
  const int wm = wid >> 2, wn = wid & 3;         // 2M x 4N
  const int fr = lane & 15;
  const int fk = (lane >> 4) << 3;
  const int row0 = (lane >> 4) << 2;

  #pragma unroll
  for (int nb = 0; nb < 2; ++nb) {
    f32x4 acc[2][2];
    #pragma unroll
    for (int f = 0; f < 2; ++f)
      #pragma unroll
      for (int g = 0; g < 2; ++g) acc[f][g] = (f32x4){0.f,0.f,0.f,0.f};

    #pragma unroll
    for (int kt = 0; kt < 10; ++kt) {
      const int ko = (kt << 5) + fk;
      bf16x8 af[2], bfv[2];
      #pragma unroll
      for (int f = 0; f < 2; ++f) {
        const int ra = wm*32 + f*16 + fr;
        af[f] = *(const bf16x8*)&Ash[ra][(((ko >> 3) ^ (ra & 7)) << 3)];
      }
      #pragma unroll
      for (int g = 0; g < 2; ++g) {
        const int base = nb*128 + wn*32 + g*16;  // multiple of 16
        const int cbt = base >> 6;               // uniform over fr
        const int rb_ = (base & 63) + fr;        // within-tile col
        bfv[g] = *(const bf16x8*)(Bimg + (size_t)cbt * 20480 + rb_*320
                                   + (((ko >> 3) ^ (rb_ & 7)) << 3));
      }
      #pragma unroll
      for (int f = 0; f < 2; ++f)
        #pragma unroll
        for (int g = 0; g < 2; ++g)
          acc[f][g] = __builtin_amdgcn_mfma_f32_16x16x32_bf16(af[f], bfv[g], acc[f][g], 0, 0, 0);
    }

    #pragma unroll
    for (int f = 0; f < 2; ++f) {
      const int gm0 = m0 + wm*32 + f*16 + row0;
      #pragma unroll
      for (int g = 0; g < 2; ++g) {
        const int col = nb*128 + wn*32 + g*16 + fr;
        if (col < 200) {
          const float bv = bias[col];
          #pragma unroll
          for (int r2 = 0; r2 < 4; ++r2)
            Cv[(size_t)(gm0 + r2) * 200 + col] = (__bf16)(acc[f][g][r2] + bv);
        }
      }
    }
  }
}

// ---------------------------------------------------------------------------
// bgemm: B-resident MFMA GEMM, pre-swizzled B image (modes 1, 2).
// ---------------------------------------------------------------------------
template<int MODE, int NK, int KSP, int NCB>
__global__ __launch_bounds__(256) void bgemm_k(
    const void* __restrict__ a0, const void* __restrict__ a1,
    const __bf16* __restrict__ Bimg, const float* __restrict__ bias,
    __bf16* __restrict__ Cv, int Ncols, const int* __restrict__ spkm)
{
  __shared__ __align__(16) __bf16 Bsh[64][KSP];
  const int tid = threadIdx.x;
  constexpr int NWT = 440 * NCB;
  constexpr int q = NWT >> 3;
  const int bid = blockIdx.x;
  const int w = (bid & 7) * q + (bid >> 3);
  const int m0 = (w / NCB) << 6;
  const int cb = w % NCB;
  const int n0 = cb << 6;

  {
    const bf16x8* src = (const bf16x8*)(Bimg + (size_t)cb * (64 * KSP));
    bf16x8* dst = (bf16x8*)&Bsh[0][0];
    constexpr int NIT = (64 * KSP / 8) / 256;
    #pragma unroll
    for (int c = 0; c < NIT; ++c) dst[c * 256 + tid] = src[c * 256 + tid];
  }
  __syncthreads();

  const int wid = tid >> 6, lane = tid & 63;
  const int wm = wid >> 1, wn = wid & 1;
  const int fr = lane & 15;
  const int fk = (lane >> 4) << 3;
  const int row0 = (lane >> 4) << 2;

  f32x4 acc[2][2];
  #pragma unroll
  for (int f = 0; f < 2; ++f)
    #pragma unroll
    for (int g = 0; g < 2; ++g) acc[f][g] = (f32x4){0.f,0.f,0.f,0.f};

  #pragma unroll
  for (int kt = 0; kt < NK; ++kt) {
    const int ko = (kt << 5) + fk;
    bf16x8 af[2];
    #pragma unroll
    for (int f = 0; f < 2; ++f) {
      const int ra = m0 + wm*32 + f*16 + fr;
      if constexpr (MODE == 2) {
        af[f] = (ko < 200)
              ? *(const bf16x8*)((const __bf16*)a0 + (size_t)ra*200 + ko)
              : *(const bf16x8*)((const __bf16*)a1 + (size_t)ra*64 + (ko - 200));
      } else {
        af[f] = *(const bf16x8*)((const __bf16*)a0 + (size_t)ra*200 + ko);
      }
    }
    bf16x8 bfv[2];
    #pragma unroll
    for (int g = 0; g < 2; ++g) {
      const int rb_ = wn*32 + g*16 + fr;
      bfv[g] = *(const bf16x8*)&Bsh[rb_][(((ko >> 3) ^ (rb_ & 7)) << 3)];
    }
    #pragma unroll
    for (int f = 0; f < 2; ++f)
      #pragma unroll
      for (int g = 0; g < 2; ++g)
        acc[f][g] = __builtin_amdgcn_mfma_f32_16x16x32_bf16(af[f], bfv[g], acc[f][g], 0, 0, 0);
  }

  #pragma unroll
  for (int f = 0; f < 2; ++f) {
    const int gm0 = m0 + wm*32 + f*16 + row0;
    int sp[4];
    if constexpr (MODE == 1) {
      #pragma unroll
      for (int r2 = 0; r2 < 4; ++r2) sp[r2] = spkm[gm0 + r2];
    }
    #pragma unroll
    for (int g = 0; g < 2; ++g) {
      const int col = n0 + wn*32 + g*16 + fr;
      if (col < Ncols) {
        const float bv = bias ? bias[col] : 0.f;
        #pragma unroll
        for (int r2 = 0; r2 < 4; ++r2) {
          const float v = acc[f][g][r2] + bv;
          const int gm = gm0 + r2;
          bool dow = true;
          if constexpr (MODE == 1) dow = (cb == 8) || ((cb >> 2) == sp[r2]);
          if (dow) Cv[(size_t)gm * Ncols + col] = (__bf16)v;
        }
      }
    }
  }
}

// ---------------------------------------------------------------------------
// dialog_k: fused RGCN mean-agg + window-sum + GraphConv GEMM (round-14 cfg).
// ---------------------------------------------------------------------------
__global__ __launch_bounds__(512) void dialog_k(
    const __bf16* __restrict__ xr, const int* __restrict__ spk,
    const float* __restrict__ brg, const __bf16* __restrict__ Wgcimg,
    const float* __restrict__ brel, __bf16* __restrict__ h2)
{
  __shared__ __align__(16) __bf16 Xsh[75][320];
  __shared__ float  h1f[65][68];
  __shared__ __align__(16) __bf16 aggbf[56][72];
  __shared__ int ssp[TT];
  __shared__ int pc[TT + 1];
  const int bid = blockIdx.x;
  const int b = bid >> 1, half = bid & 1;
  const int t0   = half ? 55 : 0;
  const int H1LO = half ? 45 : 0;
  const int XLO  = half ? 35 : 0;
  const int tid = threadIdx.x;
  if (tid < TT) ssp[tid] = spk[tid * BBD + b];
  __syncthreads();
  if (tid < 64) {
    int v = (tid < TT) ? ssp[tid] : 0;
    #pragma unroll
    for (int o = 1; o < 64; o <<= 1) { const int u = __shfl_up(v, o); if (tid >= o) v += u; }
    pc[tid + 1] = v;
    const int tot = __shfl(v, 63);
    int v2 = (tid + 64 < TT) ? ssp[tid + 64] : 0;
    #pragma unroll
    for (int o = 1; o < 64; o <<= 1) { const int u = __shfl_up(v2, o); if (tid >= o) v2 += u; }
    if (tid + 64 < TT) pc[tid + 65] = tot + v2;
    if (tid == 0) pc[0] = 0;
  }
  for (int i = tid << 3; i < 75 * 320; i += 512 << 3) {
    const int xl = i / 320, off = i - xl * 320;
    const int j = XLO + xl;
    const size_t base = ((size_t)j * BBD + b) * 576;
    const int col = (off < 256) ? ((ssp[j] << 8) + off) : (256 + off);
    *(bf16x8*)&Xsh[xl][off] = *(const bf16x8*)&xr[base + col];
  }
  __syncthreads();
  const int w8 = tid >> 6, lane = tid & 63;
  const float bias = brg[lane];
  for (int lh = w8; lh < 65; lh += 8) {
    const int t = H1LO + lh;
    const int si2 = ssp[t] << 1;
    const int jlo = imax(t - WIN, 0), jhi = imin(t + WIN, TT - 1);
    const int n1d0 = pc[t] - pc[jlo];
    const int n0d0 = (t - jlo) - n1d0;
    const int n1d1 = pc[jhi + 1] - pc[t];
    const int n0d1 = (jhi - t + 1) - n1d1;
    const float r00 = 1.f / (float)imax(n0d0, 1);
    const float r10 = 1.f / (float)imax(n1d0, 1);
    const float r01 = 1.f / (float)imax(n0d1, 1);
    const float r11 = 1.f / (float)imax(n1d1, 1);
    float a = 0.f;
    if (t >= WIN && t < TT - WIN) {
      #pragma unroll
      for (int dj = -WIN; dj <= WIN; ++dj) {
        const int j = t + dj;
        const float v = (float)Xsh[j - XLO][((si2 + ((dj >= 0) ? 1 : 0)) << 6) + lane];
        const float w = (dj >= 0) ? (ssp[j] ? r11 : r01) : (ssp[j] ? r10 : r00);
        a = fmaf(w, v, a);
      }
    } else {
      #pragma unroll
      for (int dj = -WIN; dj <= WIN; ++dj) {
        const int j = t + dj;
        const int jc = imin(imax(j, XLO), XLO + 74);
        const float v = (float)Xsh[jc - XLO][((si2 + ((dj >= 0) ? 1 : 0)) << 6) + lane];
        float w = (dj >= 0) ? (ssp[jc] ? r11 : r01) : (ssp[jc] ? r10 : r00);
        if (j < 0 || j >= TT) w = 0.f;
        a = fmaf(w, v, a);
      }
    }
    a += (float)Xsh[t - XLO][256 + lane] + bias;
    h1f[lh][lane] = a;
  }
  __syncthreads();
  for (int lt = w8; lt < 55; lt += 8) {
    const int t = t0 + lt;
    float a = 0.f;
    if (t >= WIN && t < TT - WIN) {
      #pragma unroll
      for (int dj = -WIN; dj <= WIN; ++dj)
        a += h1f[t + dj - H1LO][lane];
    } else {
      #pragma unroll
      for (int dj = -WIN; dj <= WIN; ++dj) {
        const int j = t + dj;
        const int jc = imin(imax(j, H1LO), H1LO + 64);
        const float m = ((j >= 0) && (j < TT)) ? 1.f : 0.f;
        a = fmaf(m, h1f[jc - H1LO][lane], a);
      }
    }
    aggbf[lt][lane] = (__bf16)a;
  }
  __syncthreads();
  if (w8 < 4) {
    const int wm = w8 >> 1, wn = w8 & 1;
    const int fr = lane & 15, fk = (lane >> 4) << 3, row0 = (lane >> 4) << 2;
    const int lhh = t0 - H1LO;
    f32x4 acc[2][2];
    #pragma unroll
    for (int f = 0; f < 2; ++f)
      #pragma unroll
      for (int g = 0; g < 2; ++g) acc[f][g] = (f32x4){0.f,0.f,0.f,0.f};
    #pragma unroll
    for (int kt = 0; kt < 4; ++kt) {
      const int ko = (kt << 5) + fk;
      bf16x8 af[2];
      #pragma unroll
      for (int f = 0; f < 2; ++f) {
        const int tr = wm*32 + f*16 + fr;
        if (tr < 55) {
          if (ko < 64) {
            af[f] = *(const bf16x8*)&aggbf[tr][ko];
          } else {
            const float* src = &h1f[tr + lhh][ko - 64];
            const float4 u0 = ((const float4*)src)[0];
            const float4 u1 = ((const float4*)src)[1];
            af[f] = (bf16x8){(__bf16)u0.x,(__bf16)u0.y,(__bf16)u0.z,(__bf16)u0.w,
                             (__bf16)u1.x,(__bf16)u1.y,(__bf16)u1.z,(__bf16)u1.w};
          }
        } else af[f] = (bf16x8){0,0,0,0,0,0,0,0};
      }
      bf16x8 bfv[2];
      #pragma unroll
      for (int g = 0; g < 2; ++g) {
        const int rb_ = wn*32 + g*16 + fr;
        bfv[g] = *(const bf16x8*)(Wgcimg + rb_*128 + (((ko >> 3) ^ (rb_ & 7)) << 3));
      }
      #pragma unroll
      for (int f = 0; f < 2; ++f)
        #pragma unroll
        for (int g = 0; g < 2; ++g)
          acc[f][g] = __builtin_amdgcn_mfma_f32_16x16x32_bf16(af[f], bfv[g], acc[f][g], 0, 0, 0);
    }
    #pragma unroll
    for (int g = 0; g < 2; ++g) {
      const int col = wn*32 + g*16 + fr;
      const float bv = brel[col];
      #pragma unroll
      for (int f = 0; f < 2; ++f) {
        const int tr0 = wm*32 + f*16 + row0;
        #pragma unroll
        for (int r2 = 0; r2 < 4; ++r2) {
          const int tr = tr0 + r2;
          if (tr < 55) {
            const int t = t0 + tr;
            h2[((size_t)t * BBD + b) * 64 + col] = (__bf16)(acc[f][g][r2] + bv);
          }
        }
      }
    }
  }
}

// ---------------------------------------------------------------------------
// attn_fused: MFMA matching attention + hidden GEMM + logits + log_softmax.
// ---------------------------------------------------------------------------
__global__ __launch_bounds__(448) void attn_fused_k(
    const __bf16* __restrict__ x, const __bf16* __restrict__ h2,
    const __bf16* __restrict__ Xq, const __bf16* __restrict__ Wlimg,
    const float* __restrict__ bl, const float* __restrict__ Wsm,
    const float* __restrict__ bsm, float* __restrict__ out)
{
  __shared__ __align__(16) __bf16 Msh [TT ][272];
  __shared__ __align__(16) __bf16 MTsh[264][136];
  __shared__ __align__(16) __bf16 Ash [112][136];
  const int b = blockIdx.x;
  const int tid = threadIdx.x;

  for (int idx = tid; idx < TT * 66; idx += 448) {
    const int s = idx / 66, c4 = idx % 66;
    const size_t node = (size_t)s * BBD + b;
    bf16x4 pk;
    if (c4 < 50) pk = *(const bf16x4*)&x [node * 200 + (c4 << 2)];
    else         pk = *(const bf16x4*)&h2[node * 64 + ((c4 - 50) << 2)];
    *(bf16x4*)&Msh[s][c4 << 2] = pk;
    const int d = c4 << 2;
    MTsh[d+0][s] = pk[0]; MTsh[d+1][s] = pk[1];
    MTsh[d+2][s] = pk[2]; MTsh[d+3][s] = pk[3];
  }
  for (int idx = tid; idx < 264 * 26; idx += 448) MTsh[idx / 26][110 + idx % 26] = (__bf16)0.f;
  for (int idx = tid; idx < 112 * 24; idx += 448) Ash[idx / 24][112 + idx % 24] = (__bf16)0.f;
  __syncthreads();

  const int wid = tid >> 6, lane = tid & 63;
  const int t0 = wid << 4;
  const int fr = lane & 15;
  const int g  = lane >> 4;
  const int fk = g << 3;
  const int row0 = g << 2;

  f32x4 sacc[7];
  #pragma unroll
  for (int st = 0; st < 7; ++st) sacc[st] = (f32x4){0.f,0.f,0.f,0.f};
  const int trow = t0 + fr;
  const size_t arow = ((size_t)(trow < TT ? trow : TT - 1) * BBD + b) * 264;
  for (int kst = 0; kst < 9; ++kst) {
    const int k0 = kst << 5;
    bf16x8 aq;
    if (kst < 8 || fk == 0) aq = *(const bf16x8*)&Xq[arow + k0 + fk];
    else aq = (bf16x8){0,0,0,0,0,0,0,0};
    #pragma unroll
    for (int st = 0; st < 7; ++st) {
      bf16x8 bq;
      if (kst < 8) bq = *(const bf16x8*)&Msh[st*16 + fr][k0 + fk];
      else bq = (fk == 0) ? *(const bf16x8*)&Msh[st*16 + fr][256]
                          : (bf16x8){0,0,0,0,0,0,0,0};
      sacc[st] = __builtin_amdgcn_mfma_f32_16x16x32_bf16(aq, bq, sacc[st], 0, 0, 0);
    }
  }

  #pragma unroll
  for (int r = 0; r < 4; ++r) {
    float tv[7];
    #pragma unroll
    for (int st = 0; st < 7; ++st) {
      const float e2 = __expf(2.f * sacc[st][r]);
      tv[st] = 1.f - 2.f / (e2 + 1.f);
    }
    if (fr >= 14) tv[6] = -3.0e38f;
    float mx = fmaxf(fmaxf(fmaxf(tv[0],tv[1]), fmaxf(tv[2],tv[3])),
                     fmaxf(fmaxf(tv[4],tv[5]), tv[6]));
    #pragma unroll
    for (int o = 8; o >= 1; o >>= 1) mx = fmaxf(mx, __shfl_xor(mx, o, 16));
    float e[7], sum = 0.f;
    #pragma unroll
    for (int st = 0; st < 7; ++st) { e[st] = __expf(tv[st] - mx); sum += e[st]; }
    #pragma unroll
    for (int o = 8; o >= 1; o >>= 1) sum += __shfl_xor(sum, o, 16);
    const float inv = 1.f / sum;
    const int tr = t0 + (g << 2) + r;
    #pragma unroll
    for (int st = 0; st < 7; ++st) Ash[tr][st*16 + fr] = (__bf16)(e[st] * inv);
  }
  __syncthreads();

  __bf16 (*attsh)[272] = Msh;
  const int tr2 = t0 + (g << 2);
  for (int dt = 0; dt < 17; ++dt) {
    const int d0 = dt << 4;
    f32x4 pacc = (f32x4){0.f,0.f,0.f,0.f};
    #pragma unroll
    for (int kst = 0; kst < 4; ++kst) {
      const int k0 = kst << 5;
      const bf16x8 pa = *(const bf16x8*)&Ash [t0 + fr][k0 + fk];
      const bf16x8 pb = *(const bf16x8*)&MTsh[d0 + fr][k0 + fk];
      pacc = __builtin_amdgcn_mfma_f32_16x16x32_bf16(pa, pb, pacc, 0, 0, 0);
    }
    const int col = d0 + fr;
    if (col < 264) {
      #pragma unroll
      for (int r = 0; r < 4; ++r) {
        const int t = tr2 + r;
        if (t < TT) attsh[t][col] = (__bf16)pacc[r];
      }
    }
  }
  __syncthreads();

  float* Wssh = (float*)&MTsh[0][0];
  for (int i = tid; i < 512; i += 448) {
    const int k = i >> 3, cc = i & 7;
    Wssh[(k << 3) + cc] = (cc < 7) ? Wsm[k*7 + cc] : 0.f;
  }

  float (*hidf)[68] = (float(*)[68])&Ash[0][0];
  f32x4 hacc[4];
  #pragma unroll
  for (int gg = 0; gg < 4; ++gg) hacc[gg] = (f32x4){0.f,0.f,0.f,0.f};
  #pragma unroll
  for (int kst = 0; kst < 9; ++kst) {
    const int ko = (kst << 5) + fk;
    const int ar = t0 + fr;
    bf16x8 af;
    if (ko < 264 && ar < TT) af = *(const bf16x8*)&attsh[ar][ko];
    else af = (bf16x8){0,0,0,0,0,0,0,0};
    #pragma unroll
    for (int gg = 0; gg < 4; ++gg) {
      const int rb_ = gg*16 + fr;
      const bf16x8 bfv = *(const bf16x8*)(Wlimg + rb_*320 + (((ko >> 3) ^ (rb_ & 7)) << 3));
      hacc[gg] = __builtin_amdgcn_mfma_f32_16x16x32_bf16(af, bfv, hacc[gg], 0, 0, 0);
    }
  }
  #pragma unroll
  for (int gg = 0; gg < 4; ++gg) {
    const int col = gg*16 + fr;
    const float bv = bl[col];
    #pragma unroll
    for (int r = 0; r < 4; ++r) {
      const int row = t0 + row0 + r;
      if (row < TT) hidf[row][col] = fmaxf(hacc[gg][r] + bv, 0.f);
    }
  }
  __syncthreads();

  const int c = tid & 7;
  const float bc = (c < 7) ? bsm[c] : 0.f;
  #pragma unroll
  for (int p = 0; p < 2; ++p) {
    const int lr = p * 56 + (tid >> 3);
    if (lr < TT) {
      float lg = -3.0e38f;
      if (c < 7) {
        lg = bc;
        #pragma unroll
        for (int k = 0; k < 64; ++k) lg += hidf[lr][k] * Wssh[(k << 3) + c];
      }
      float mx = lg;
      #pragma unroll
      for (int o = 4; o >= 1; o >>= 1) mx = fmaxf(mx, __shfl_xor(mx, o, 8));
      float e = (c < 7) ? __expf(lg - mx) : 0.f;
      float sm = e;
      #pragma unroll
      for (int o = 4; o >= 1; o >>= 1) sm += __shfl_xor(sm, o, 8);
      if (c < 7) out[((size_t)b * TT + lr) * 7 + c] = lg - mx - __logf(sm);
    }
  }
}

// ---------------------------------------------------------------------------
extern "C" void kernel_launch(void* const* d_in, const int* in_sizes, int n_in,
                              void* d_out, int out_size, void* d_ws, size_t ws_size,
                              hipStream_t stream)
{
  const float* textf  = (const float*)d_in[0];
  const float* acouf  = (const float*)d_in[1];
  const float* visuf  = (const float*)d_in[2];
  const int*   spk    = (const int*)  d_in[3];
  const float* Wf     = (const float*)d_in[4];
  const float* bfv    = (const float*)d_in[5];
  const float* basis  = (const float*)d_in[6];
  const float* comp   = (const float*)d_in[7];
  const float* root   = (const float*)d_in[8];
  const float* brg    = (const float*)d_in[9];
  const float* Wrel   = (const float*)d_in[10];
  const float* brel   = (const float*)d_in[11];
  const float* Wroot2 = (const float*)d_in[12];
  const float* Wma    = (const float*)d_in[13];
  const float* bma    = (const float*)d_in[14];
  const float* Wl     = (const float*)d_in[15];
  const float* bl     = (const float*)d_in[16];
  const float* Wsm    = (const float*)d_in[17];
  const float* bsm    = (const float*)d_in[18];

  float* ws = (float*)d_ws;
  float*  wrels = ws;                               // @0        (115,200 f32)
  __bf16* img   = (__bf16*)(ws + 115200);           // 360,448 bf16 images
  __bf16* xb    = (__bf16*)(ws + 4801024);          // N*200 bf16
  __bf16* xr    = (__bf16*)(ws + 7617024);          // N*576 bf16
  __bf16* h2    = (__bf16*)(ws + 15727104);         // N*64 bf16
  __bf16* Xqb   = (__bf16*)(ws + 16628224);         // N*264 bf16
  float*  outp  = (float*)d_out;

  __bf16* Wfimg  = img;
  __bf16* wrimg  = img + 81920;
  __bf16* Wmaimg = img + 229376;
  __bf16* Wlimg  = img + 331776;
  __bf16* Wgcimg = img + 352256;

  wrels_k<<<450, 256, 0, stream>>>(basis, comp, root, wrels);
  prep_k<<<176, 256, 0, stream>>>(wrels, Wf, Wma, Wl, Wrel, Wroot2, img);
  bgemm0_k<<<440, 512, 0, stream>>>(textf, acouf, visuf, Wfimg, bfv, xb);
  bgemm_k<1,7,256,9><<<3960, 256, 0, stream>>>(xb, nullptr, wrimg, nullptr, xr, 576, spk);
  dialog_k<<<512, 512, 0, stream>>>(xr, spk, brg, Wgcimg, brel, h2);
  bgemm_k<2,9,320,5><<<2200, 256, 0, stream>>>(xb, h2, Wmaimg, bma, Xqb, 264, nullptr);
  attn_fused_k<<<256, 448, 0, stream>>>(xb, h2, Xqb, Wlimg, bl, Wsm, bsm, outp);
}